// Round 4
// baseline (296.179 us; speedup 1.0000x reference)
//
#include <hip/hip_runtime.h>
#include <hip/hip_bf16.h>
#include <hip/hip_cooperative_groups.h>

namespace cg = cooperative_groups;

#define NN 8192

typedef float f32x4 __attribute__((ext_vector_type(4)));

__device__ __forceinline__ float lif_activation(
    float I, float x, float vv, float el, float tm)
{
    const float arg   = 12.0f * I / 8192.0f;
    const float Isig  = 1.0f / (1.0f + expf(-arg));
    const float Ifull = Isig + 0.9f * x;
    const float v_next = vv + (el - vv + Ifull * (30.0f - el)) / tm;
    return 1.0f / (1.0f + expf(30.0f - v_next));
}

// Fused: split-K GEMV partials -> grid sync -> deterministic reduce + pointwise.
// Grid (8, S) = 8*S blocks of 256 threads; with S=128 that's 1024 blocks = 4/CU.
template <int S>
__global__ __launch_bounds__(256, 4) void lif_fused(
    const float* __restrict__ g, const float* __restrict__ w,
    float* __restrict__ partial,
    const float* __restrict__ x_in, const float* __restrict__ v,
    const float* __restrict__ E_L, const float* __restrict__ tau_m,
    float* __restrict__ out)
{
    constexpr int RPS = NN / S;
    const int col = blockIdx.x * 1024 + threadIdx.x * 4;
    const int s   = blockIdx.y;
    const int r0  = s * RPS;

    const float* wp = w + (size_t)r0 * NN + col;
    const float* gp = g + r0;

    f32x4 acc = {0.f, 0.f, 0.f, 0.f};
    #pragma unroll 8
    for (int i = 0; i < RPS; ++i) {
        const float gi = gp[i];                       // wave-uniform scalar load
        const f32x4 wv = *reinterpret_cast<const f32x4*>(wp + (size_t)i * NN);
        acc.x = fmaf(gi, wv.x, acc.x);
        acc.y = fmaf(gi, wv.y, acc.y);
        acc.z = fmaf(gi, wv.z, acc.z);
        acc.w = fmaf(gi, wv.w, acc.w);
    }
    *reinterpret_cast<f32x4*>(partial + (size_t)s * NN + col) = acc;

    __threadfence();            // device-scope release of partial stores
    cg::this_grid().sync();

    // First 256 linear blocks do the reduction + pointwise (32 cols each).
    const int b = blockIdx.y * 8 + blockIdx.x;
    if (b < 256) {
        const int cl = threadIdx.x & 31;   // column within block
        const int kg = threadIdx.x >> 5;   // split group 0..7
        const int j  = b * 32 + cl;
        constexpr int PER = S / 8;

        float a2 = 0.f;
        #pragma unroll
        for (int t = 0; t < PER; ++t)      // fixed order: deterministic
            a2 += partial[(size_t)(kg * PER + t) * NN + j];

        __shared__ float red[8][32];
        red[kg][cl] = a2;
        __syncthreads();

        if (threadIdx.x < 32) {
            float I = red[0][cl];
            #pragma unroll
            for (int k = 1; k < 8; ++k) I += red[k][cl];   // fixed order
            out[j] = lif_activation(I, x_in[j], v[j], E_L[j], tau_m[j]);
        }
    }
}

// ---------- fallback two-kernel path (only if ws_size < 4 MB) ----------
__global__ __launch_bounds__(256) void lif_gemv_part_rt(
    const float* __restrict__ g, const float* __restrict__ w,
    float* __restrict__ partial, int rps)
{
    const int col = blockIdx.x * 1024 + threadIdx.x * 4;
    const int s   = blockIdx.y;
    const int r0  = s * rps;
    const float* wp = w + (size_t)r0 * NN + col;
    const float* gp = g + r0;
    f32x4 acc = {0.f, 0.f, 0.f, 0.f};
    #pragma unroll 8
    for (int i = 0; i < rps; ++i) {
        const float gi = gp[i];
        const f32x4 wv = *reinterpret_cast<const f32x4*>(wp + (size_t)i * NN);
        acc.x = fmaf(gi, wv.x, acc.x);
        acc.y = fmaf(gi, wv.y, acc.y);
        acc.z = fmaf(gi, wv.z, acc.z);
        acc.w = fmaf(gi, wv.w, acc.w);
    }
    *reinterpret_cast<f32x4*>(partial + (size_t)s * NN + col) = acc;
}

__global__ __launch_bounds__(256) void lif_pointwise_rt(
    const float* __restrict__ partial, int nsplits,
    const float* __restrict__ x_in, const float* __restrict__ v,
    const float* __restrict__ E_L, const float* __restrict__ tau_m,
    float* __restrict__ out)
{
    const int j = blockIdx.x * blockDim.x + threadIdx.x;
    if (j >= NN) return;
    float I = 0.f;
    for (int s = 0; s < nsplits; ++s)
        I += partial[(size_t)s * NN + j];
    out[j] = lif_activation(I, x_in[j], v[j], E_L[j], tau_m[j]);
}
// -----------------------------------------------------------------------

extern "C" void kernel_launch(void* const* d_in, const int* in_sizes, int n_in,
                              void* d_out, int out_size, void* d_ws, size_t ws_size,
                              hipStream_t stream) {
    const float* x_in  = (const float*)d_in[0];
    const float* v     = (const float*)d_in[1];
    const float* g     = (const float*)d_in[2];
    const float* w     = (const float*)d_in[3];
    const float* E_L   = (const float*)d_in[4];
    const float* tau_m = (const float*)d_in[5];
    // d_in[6] = tau_g, unused by the reference
    float* out     = (float*)d_out;
    float* partial = (float*)d_ws;

    constexpr int S = 128;
    if ((size_t)S * NN * sizeof(float) <= ws_size) {
        void* args[] = { (void*)&g, (void*)&w, (void*)&partial,
                         (void*)&x_in, (void*)&v, (void*)&E_L, (void*)&tau_m,
                         (void*)&out };
        hipLaunchCooperativeKernel((void*)lif_fused<S>, dim3(8, S), dim3(256),
                                   args, 0, stream);
    } else {
        int Sf = 64;
        while (Sf > 1 && (size_t)Sf * NN * sizeof(float) > ws_size) Sf >>= 1;
        dim3 grid1(NN / 1024, Sf);
        lif_gemv_part_rt<<<grid1, 256, 0, stream>>>(g, w, partial, NN / Sf);
        lif_pointwise_rt<<<NN / 256, 256, 0, stream>>>(partial, Sf, x_in, v, E_L, tau_m, out);
    }
}

// Round 6
// 159.914 us; speedup vs baseline: 1.8521x; 1.8521x over previous
//
#include <hip/hip_runtime.h>
#include <hip/hip_bf16.h>

#define NN 8192

typedef float f32x4 __attribute__((ext_vector_type(4)));

__device__ __forceinline__ float lif_activation(
    float I, float x, float vv, float el, float tm)
{
    const float arg   = 12.0f * I / 8192.0f;
    const float Isig  = 1.0f / (1.0f + expf(-arg));
    const float Ifull = Isig + 0.9f * x;
    const float v_next = vv + (el - vv + Ifull * (30.0f - el)) / tm;
    return 1.0f / (1.0f + expf(30.0f - v_next));
}

// Fused single dispatch: split-K GEMV partials + lightweight counter barrier +
// deterministic reduce/pointwise in the first 256 linear blocks.
// Grid (8,128) = 1024 blocks of 256 threads; VGPR is low so 4 blocks/CU resident.
__global__ __launch_bounds__(256, 4) void lif_fused_spin(
    const float* __restrict__ g, const float* __restrict__ w,
    float* __restrict__ partial, int* __restrict__ counter,
    const float* __restrict__ x_in, const float* __restrict__ v,
    const float* __restrict__ E_L, const float* __restrict__ tau_m,
    float* __restrict__ out)
{
    constexpr int S   = 128;
    constexpr int RPS = NN / S;       // 64
    const int col = blockIdx.x * 1024 + threadIdx.x * 4;
    const int s   = blockIdx.y;
    const int r0  = s * RPS;

    const float* wp = w + (size_t)r0 * NN + col;
    const float* gp = g + r0;

    f32x4 acc = {0.f, 0.f, 0.f, 0.f};
    #pragma unroll 8
    for (int i = 0; i < RPS; ++i) {
        const float gi = gp[i];                       // wave-uniform scalar load
        const f32x4 wv = *reinterpret_cast<const f32x4*>(wp + (size_t)i * NN);
        acc.x = fmaf(gi, wv.x, acc.x);
        acc.y = fmaf(gi, wv.y, acc.y);
        acc.z = fmaf(gi, wv.z, acc.z);
        acc.w = fmaf(gi, wv.w, acc.w);
    }
    *reinterpret_cast<f32x4*>(partial + (size_t)s * NN + col) = acc;
    __syncthreads();                                   // all stores in block issued

    if (threadIdx.x == 0) {
        // RELEASE: flushes this block's partial stores to the coherence point.
        __hip_atomic_fetch_add(counter, 1, __ATOMIC_RELEASE, __HIP_MEMORY_SCOPE_AGENT);
    }

    const int b = blockIdx.y * 8 + blockIdx.x;         // linear block id
    if (b >= 256) return;                              // producers exit

    if (threadIdx.x == 0) {
        while (__hip_atomic_load(counter, __ATOMIC_RELAXED, __HIP_MEMORY_SCOPE_AGENT) < 8 * S)
            __builtin_amdgcn_s_sleep(2);
    }
    __syncthreads();
    // ACQUIRE: invalidate stale L1/L2 lines before reading other blocks' partials.
    __builtin_amdgcn_fence(__ATOMIC_ACQUIRE, "agent");

    const int cl = threadIdx.x & 31;   // column within block
    const int kg = threadIdx.x >> 5;   // split group 0..7
    const int j  = b * 32 + cl;
    constexpr int PER = S / 8;         // 16

    float a2 = 0.f;
    #pragma unroll
    for (int t = 0; t < PER; ++t)      // fixed order: deterministic
        a2 += partial[(size_t)(kg * PER + t) * NN + j];

    __shared__ float red[8][32];
    red[kg][cl] = a2;
    __syncthreads();

    if (threadIdx.x < 32) {
        float I = red[0][cl];
        #pragma unroll
        for (int k = 1; k < 8; ++k) I += red[k][cl];   // fixed order
        out[j] = lif_activation(I, x_in[j], v[j], E_L[j], tau_m[j]);
    }
}

// ---------- proven R3 two-kernel path (fallback / safety) ----------
__global__ __launch_bounds__(256) void lif_gemv_part_rt(
    const float* __restrict__ g, const float* __restrict__ w,
    float* __restrict__ partial, int rps)
{
    const int col = blockIdx.x * 1024 + threadIdx.x * 4;
    const int s   = blockIdx.y;
    const int r0  = s * rps;
    const float* wp = w + (size_t)r0 * NN + col;
    const float* gp = g + r0;
    f32x4 acc = {0.f, 0.f, 0.f, 0.f};
    #pragma unroll 8
    for (int i = 0; i < rps; ++i) {
        const float gi = gp[i];
        const f32x4 wv = *reinterpret_cast<const f32x4*>(wp + (size_t)i * NN);
        acc.x = fmaf(gi, wv.x, acc.x);
        acc.y = fmaf(gi, wv.y, acc.y);
        acc.z = fmaf(gi, wv.z, acc.z);
        acc.w = fmaf(gi, wv.w, acc.w);
    }
    *reinterpret_cast<f32x4*>(partial + (size_t)s * NN + col) = acc;
}

__global__ __launch_bounds__(256) void lif_pointwise_rt(
    const float* __restrict__ partial, int nsplits,
    const float* __restrict__ x_in, const float* __restrict__ v,
    const float* __restrict__ E_L, const float* __restrict__ tau_m,
    float* __restrict__ out)
{
    const int j = blockIdx.x * blockDim.x + threadIdx.x;
    if (j >= NN) return;
    float I = 0.f;
    for (int s = 0; s < nsplits; ++s)
        I += partial[(size_t)s * NN + j];
    out[j] = lif_activation(I, x_in[j], v[j], E_L[j], tau_m[j]);
}
// -------------------------------------------------------------------

extern "C" void kernel_launch(void* const* d_in, const int* in_sizes, int n_in,
                              void* d_out, int out_size, void* d_ws, size_t ws_size,
                              hipStream_t stream) {
    const float* x_in  = (const float*)d_in[0];
    const float* v     = (const float*)d_in[1];
    const float* g     = (const float*)d_in[2];
    const float* w     = (const float*)d_in[3];
    const float* E_L   = (const float*)d_in[4];
    const float* tau_m = (const float*)d_in[5];
    // d_in[6] = tau_g, unused by the reference
    float* out     = (float*)d_out;
    float* partial = (float*)d_ws;

    constexpr int    S          = 128;
    constexpr size_t PART_BYTES = (size_t)S * NN * sizeof(float);   // 4 MB

    if (ws_size >= PART_BYTES + 64) {
        int* counter = (int*)((char*)d_ws + PART_BYTES);
        (void)hipMemsetAsync(counter, 0, sizeof(int), stream);   // graph-capturable
        lif_fused_spin<<<dim3(8, S), 256, 0, stream>>>(
            g, w, partial, counter, x_in, v, E_L, tau_m, out);
    } else {
        int Sf = 64;
        while (Sf > 1 && (size_t)Sf * NN * sizeof(float) > ws_size) Sf >>= 1;
        dim3 grid1(NN / 1024, Sf);
        lif_gemv_part_rt<<<grid1, 256, 0, stream>>>(g, w, partial, NN / Sf);
        lif_pointwise_rt<<<NN / 256, 256, 0, stream>>>(partial, Sf, x_in, v, E_L, tau_m, out);
    }
}

// Round 7
// 49.173 us; speedup vs baseline: 6.0232x; 3.2520x over previous
//
#include <hip/hip_runtime.h>
#include <hip/hip_bf16.h>

#define NN 8192

typedef float f32x4 __attribute__((ext_vector_type(4)));

// Phase 1: split-K GEMV partials. partial[s][j] = sum_{i in split s} g_i * w[i][j]
// R3-proven inner loop: runtime rps, unroll 8, plain (cache-friendly) loads.
__global__ __launch_bounds__(256) void lif_gemv_part(
    const float* __restrict__ g, const float* __restrict__ w,
    float* __restrict__ partial, int rows_per_split)
{
    const int col = blockIdx.x * 1024 + threadIdx.x * 4;
    const int s   = blockIdx.y;
    const int r0  = s * rows_per_split;

    const float* wp = w + (size_t)r0 * NN + col;
    const float* gp = g + r0;

    f32x4 acc = {0.f, 0.f, 0.f, 0.f};
    #pragma unroll 8
    for (int i = 0; i < rows_per_split; ++i) {
        const float gi = gp[i];                       // wave-uniform scalar load
        const f32x4 wv = *reinterpret_cast<const f32x4*>(wp + (size_t)i * NN);
        acc.x = fmaf(gi, wv.x, acc.x);
        acc.y = fmaf(gi, wv.y, acc.y);
        acc.z = fmaf(gi, wv.z, acc.z);
        acc.w = fmaf(gi, wv.w, acc.w);
    }
    *reinterpret_cast<f32x4*>(partial + (size_t)s * NN + col) = acc;
}

__device__ __forceinline__ float lif_activation(
    float I, float x, float vv, float el, float tm)
{
    const float arg   = 12.0f * I / 8192.0f;
    const float Isig  = 1.0f / (1.0f + expf(-arg));
    const float Ifull = Isig + 0.9f * x;
    const float v_next = vv + (el - vv + Ifull * (30.0f - el)) / tm;
    return 1.0f / (1.0f + expf(30.0f - v_next));
}

// Phase 2: parallel deterministic reduction + LIF pointwise.
// 256 blocks x 256 threads; block owns 32 columns; 8 split-groups per column.
template <int S>
__global__ __launch_bounds__(256) void lif_pointwise_t(
    const float* __restrict__ partial,
    const float* __restrict__ x_in, const float* __restrict__ v,
    const float* __restrict__ E_L, const float* __restrict__ tau_m,
    float* __restrict__ out)
{
    const int cl = threadIdx.x & 31;   // column within block
    const int kg = threadIdx.x >> 5;   // split group 0..7
    const int j  = blockIdx.x * 32 + cl;
    constexpr int PER = S / 8;

    float acc = 0.f;
    #pragma unroll
    for (int s = 0; s < PER; ++s)      // fixed order: deterministic
        acc += partial[(size_t)(kg * PER + s) * NN + j];

    __shared__ float red[8][32];
    red[kg][cl] = acc;
    __syncthreads();

    if (threadIdx.x < 32) {
        float I = red[0][cl];
        #pragma unroll
        for (int k = 1; k < 8; ++k) I += red[k][cl];   // fixed order
        out[j] = lif_activation(I, x_in[j], v[j], E_L[j], tau_m[j]);
    }
}

// Runtime fallback (any nsplits).
__global__ __launch_bounds__(256) void lif_pointwise_rt(
    const float* __restrict__ partial, int nsplits,
    const float* __restrict__ x_in, const float* __restrict__ v,
    const float* __restrict__ E_L, const float* __restrict__ tau_m,
    float* __restrict__ out)
{
    const int j = blockIdx.x * blockDim.x + threadIdx.x;
    if (j >= NN) return;
    float I = 0.f;
    for (int s = 0; s < nsplits; ++s)
        I += partial[(size_t)s * NN + j];
    out[j] = lif_activation(I, x_in[j], v[j], E_L[j], tau_m[j]);
}

extern "C" void kernel_launch(void* const* d_in, const int* in_sizes, int n_in,
                              void* d_out, int out_size, void* d_ws, size_t ws_size,
                              hipStream_t stream) {
    const float* x_in  = (const float*)d_in[0];
    const float* v     = (const float*)d_in[1];
    const float* g     = (const float*)d_in[2];
    const float* w     = (const float*)d_in[3];
    const float* E_L   = (const float*)d_in[4];
    const float* tau_m = (const float*)d_in[5];
    // d_in[6] = tau_g, unused by the reference
    float* out     = (float*)d_out;
    float* partial = (float*)d_ws;

    // S=256 -> 2048 blocks = 8/CU = 100% occupancy (sole change vs R3's 50us).
    int S = 256;
    while (S > 1 && (size_t)S * NN * sizeof(float) > ws_size) S >>= 1;

    dim3 grid1(NN / 1024, S);
    lif_gemv_part<<<grid1, 256, 0, stream>>>(g, w, partial, NN / S);

    switch (S) {
        case 256: lif_pointwise_t<256><<<NN / 32, 256, 0, stream>>>(partial, x_in, v, E_L, tau_m, out); break;
        case 128: lif_pointwise_t<128><<<NN / 32, 256, 0, stream>>>(partial, x_in, v, E_L, tau_m, out); break;
        case  64: lif_pointwise_t< 64><<<NN / 32, 256, 0, stream>>>(partial, x_in, v, E_L, tau_m, out); break;
        case  32: lif_pointwise_t< 32><<<NN / 32, 256, 0, stream>>>(partial, x_in, v, E_L, tau_m, out); break;
        default:  lif_pointwise_rt<<<NN / 256, 256, 0, stream>>>(partial, S, x_in, v, E_L, tau_m, out); break;
    }
}